// Round 1
// baseline (232.514 us; speedup 1.0000x reference)
//
#include <hip/hip_runtime.h>
#include <hip/hip_bf16.h>

#define S_ 64
#define P_ 32
#define N_ 2048
#define H_ 64
#define E_ 64
#define D1_ 512
#define D2_ 1024
#define EPS_ 1e-5f

typedef unsigned short u16;
using bf16x8 = __attribute__((ext_vector_type(8))) __bf16;
using floatx4 = __attribute__((ext_vector_type(4))) float;

__device__ inline u16 f2bf(float x) {
    unsigned u = __float_as_uint(x);
    unsigned r = (u + 0x7fffu + ((u >> 16) & 1u)) >> 16;
    return (u16)r;
}
__device__ inline unsigned bf2pack(float lo, float hi) {
    return (unsigned)f2bf(lo) | ((unsigned)f2bf(hi) << 16);
}

// ---- kernel 1a: Weq[i][d] = sum_e W_embed[i][e] * W1[e][d]  (i=0,1) ----
__global__ void k_weq(const float* __restrict__ W_embed, const float* __restrict__ W1,
                      float* __restrict__ Weq) {
    int d = blockIdx.x * 256 + threadIdx.x;  // 0..511
    float a0 = 0.f, a1 = 0.f;
    for (int e = 0; e < E_; ++e) {
        float w = W1[e * D1_ + d];
        a0 += W_embed[e] * w;
        a1 += W_embed[E_ + e] * w;
    }
    Weq[d] = a0;
    Weq[D1_ + d] = a1;
}

// ---- kernel 1b: u[n,d] = pos[n]@Weq ; w[n,d] = u + h[n]@W1[64:128] ----
__global__ void k_wu(const float* __restrict__ pos, const float* __restrict__ h,
                     const float* __restrict__ W1, const float* __restrict__ Weq,
                     float* __restrict__ wbuf, float* __restrict__ ubuf) {
    __shared__ float hs[H_];
    const int n = blockIdx.x;
    const int d = threadIdx.x;  // 512 threads
    if (d < H_) hs[d] = h[n * H_ + d];
    __syncthreads();
    const float p0 = pos[n * 2], p1 = pos[n * 2 + 1];
    const float uu = p0 * Weq[d] + p1 * Weq[D1_ + d];
    float acc = 0.f;
#pragma unroll 8
    for (int e = 0; e < H_; ++e) acc += hs[e] * W1[(E_ + e) * D1_ + d];
    ubuf[(size_t)n * D1_ + d] = uu;
    wbuf[(size_t)n * D1_ + d] = uu + acc;
}

// ---- kernel 2: BN1 per-scene stats; in-place A=(w-wb)*sc+be1, B=(u-ub)*sc ----
__global__ void k_bn1(float* __restrict__ wbuf, float* __restrict__ ubuf,
                      const float* __restrict__ g1, const float* __restrict__ be1) {
    const int s = blockIdx.x;
    const int d = threadIdx.x;  // 512 threads
    const size_t base = (size_t)s * P_ * D1_ + d;
    float sw = 0.f, sww = 0.f, su = 0.f, suu = 0.f;
    for (int j = 0; j < P_; ++j) {
        float wv = wbuf[base + (size_t)j * D1_];
        float uv = ubuf[base + (size_t)j * D1_];
        sw += wv; sww += wv * wv;
        su += uv; suu += uv * uv;
    }
    const float mw = sw * (1.f / P_), mu = su * (1.f / P_);
    const float var = (sww * (1.f / P_) - mw * mw) + (suu * (1.f / P_) - mu * mu);
    const float sc = rsqrtf(var + EPS_) * g1[d];
    const float bb = be1[d];
    for (int j = 0; j < P_; ++j) {
        size_t idx = base + (size_t)j * D1_;
        wbuf[idx] = (wbuf[idx] - mw) * sc + bb;
        ubuf[idx] = (ubuf[idx] - mu) * sc;
    }
}

// ---- kernel 3: W2t[n][k] = bf16(W2[k][n])  (transpose + convert) ----
__global__ void k_w2t(const float* __restrict__ W2, u16* __restrict__ W2t) {
    __shared__ float tile[32][33];
    const int bx = blockIdx.x;  // n tile (32)
    const int by = blockIdx.y;  // k tile (16)
    const int tx = threadIdx.x, ty = threadIdx.y;  // 32x8
    for (int i = 0; i < 32; i += 8)
        tile[ty + i][tx] = W2[(size_t)(by * 32 + ty + i) * D2_ + bx * 32 + tx];
    __syncthreads();
    for (int i = 0; i < 32; i += 8)
        W2t[(size_t)(bx * 32 + ty + i) * D1_ + by * 32 + tx] = f2bf(tile[tx][ty + i]);
}

// ---- kernel 4: x1[m,d] = bf16(relu(A[s,j,d] - B[s,k,d])), m = s*1024+k*32+j ----
__global__ void k_x1(const float* __restrict__ A, const float* __restrict__ B,
                     u16* __restrict__ x1) {
    const int t = blockIdx.x * 256 + threadIdx.x;  // < 4194304
    const int d8 = t & 63;
    const int r = t >> 6;       // row m, 0..65535
    const int j = r & 31;
    const int sk = r >> 5;      // s*32 + k
    const int s = sk >> 5;
    const float4* Af = (const float4*)(A + (size_t)(s * 32 + j) * D1_ + (d8 << 3));
    const float4* Bf = (const float4*)(B + (size_t)sk * D1_ + (d8 << 3));
    float4 a0 = Af[0], a1 = Af[1];
    float4 b0 = Bf[0], b1 = Bf[1];
    uint4 o;
    o.x = bf2pack(fmaxf(a0.x - b0.x, 0.f), fmaxf(a0.y - b0.y, 0.f));
    o.y = bf2pack(fmaxf(a0.z - b0.z, 0.f), fmaxf(a0.w - b0.w, 0.f));
    o.z = bf2pack(fmaxf(a1.x - b1.x, 0.f), fmaxf(a1.y - b1.y, 0.f));
    o.w = bf2pack(fmaxf(a1.z - b1.z, 0.f), fmaxf(a1.w - b1.w, 0.f));
    *(uint4*)(x1 + ((size_t)r << 9) + (d8 << 3)) = o;
}

// ---- kernel 5: GEMM [65536x512]x[512x1024] with fused j-max/min + BN2 stats ----
__global__ __launch_bounds__(256)
void k_gemm(const u16* __restrict__ x1, const u16* __restrict__ w2t,
            float* __restrict__ maxv, float* __restrict__ minv,
            float* __restrict__ psum, float* __restrict__ psumsq) {
    __shared__ u16 As[128 * 64];
    __shared__ u16 Bs[128 * 64];
    const int bx = blockIdx.x;   // col tile 0..7
    const int by = blockIdx.y;   // row tile 0..511
    const int M0 = by << 7, N0 = bx << 7;
    const int tid = threadIdx.x;
    const int wave = tid >> 6, lane = tid & 63;
    const int wm = wave >> 1, wn = wave & 1;
    const int quad = lane >> 4, l16 = lane & 15;
    const int lrow = lane >> 3, lchk = lane & 7;
    const int gchk = lchk ^ lrow;  // XOR-swizzled global chunk for this lane

    floatx4 acc[4][4] = {};

    const int arow = wave << 5;  // this wave stages rows arow..arow+31
    for (int it = 0; it < 8; ++it) {
        const int k0 = it << 6;
#pragma unroll
        for (int t = 0; t < 4; ++t) {
            const int rbase = arow + (t << 3);
            const u16* ga = x1 + (size_t)(M0 + rbase + lrow) * 512 + (k0 + (gchk << 3));
            const u16* gb = w2t + (size_t)(N0 + rbase + lrow) * 512 + (k0 + (gchk << 3));
            __builtin_amdgcn_global_load_lds(
                (const __attribute__((address_space(1))) void*)ga,
                (__attribute__((address_space(3))) void*)(As + (rbase << 6)), 16, 0, 0);
            __builtin_amdgcn_global_load_lds(
                (const __attribute__((address_space(1))) void*)gb,
                (__attribute__((address_space(3))) void*)(Bs + (rbase << 6)), 16, 0, 0);
        }
        __syncthreads();
#pragma unroll
        for (int kk = 0; kk < 2; ++kk) {
            bf16x8 af[4], bfr[4];
#pragma unroll
            for (int tm = 0; tm < 4; ++tm) {
                const int row = (wm << 6) + (tm << 4) + l16;
                const int sc = ((kk << 2) + quad) ^ (row & 7);
                af[tm] = *(const bf16x8*)(As + (row << 6) + (sc << 3));
            }
#pragma unroll
            for (int tn = 0; tn < 4; ++tn) {
                const int row = (wn << 6) + (tn << 4) + l16;
                const int sc = ((kk << 2) + quad) ^ (row & 7);
                bfr[tn] = *(const bf16x8*)(Bs + (row << 6) + (sc << 3));
            }
#pragma unroll
            for (int tm = 0; tm < 4; ++tm)
#pragma unroll
                for (int tn = 0; tn < 4; ++tn)
                    acc[tm][tn] = __builtin_amdgcn_mfma_f32_16x16x32_bf16(
                        af[tm], bfr[tn], acc[tm][tn], 0, 0, 0);
        }
        __syncthreads();
    }

    // epilogue: reduce over j (32 rows) for max/min; 64-row partial sums for BN2
    const int s = by >> 3, rb = by & 7;
#pragma unroll
    for (int tn = 0; tn < 4; ++tn) {
        const int col = N0 + (wn << 6) + (tn << 4) + l16;
        float wsum = 0.f, wsq = 0.f;
#pragma unroll
        for (int gp = 0; gp < 2; ++gp) {
            float vmax = -3.4e38f, vmin = 3.4e38f, vs = 0.f, vq = 0.f;
#pragma unroll
            for (int tm = gp * 2; tm < gp * 2 + 2; ++tm)
#pragma unroll
                for (int r = 0; r < 4; ++r) {
                    float v = acc[tm][tn][r];
                    vmax = fmaxf(vmax, v);
                    vmin = fminf(vmin, v);
                    vs += v;
                    vq += v * v;
                }
            // reduce across quads (rows quad*4+r): lanes xor 16, 32
#pragma unroll
            for (int off = 16; off < 64; off <<= 1) {
                vmax = fmaxf(vmax, __shfl_xor(vmax, off));
                vmin = fminf(vmin, __shfl_xor(vmin, off));
                vs += __shfl_xor(vs, off);
                vq += __shfl_xor(vq, off);
            }
            if (quad == 0) {
                const int kg = (by << 2) + (wm << 1) + gp;  // global ped row 0..2047
                maxv[(size_t)kg * D2_ + col] = vmax;
                minv[(size_t)kg * D2_ + col] = vmin;
            }
            wsum += vs;
            wsq += vq;
        }
        if (quad == 0) {
            const int slot = (s << 4) + (rb << 1) + wm;  // 16 slots per scene
            psum[(size_t)slot * D2_ + col] = wsum;
            psumsq[(size_t)slot * D2_ + col] = wsq;
        }
    }
}

// ---- kernel 6: BN2 + relu on the j-maxed values ----
__global__ void k_final(const float* __restrict__ maxv, const float* __restrict__ minv,
                        const float* __restrict__ psum, const float* __restrict__ psumsq,
                        const float* __restrict__ g2, const float* __restrict__ be2,
                        float* __restrict__ out) {
    const int c = blockIdx.x * 256 + threadIdx.x;  // 0..1023
    const int s = blockIdx.y;
    float sm = 0.f, sq = 0.f;
#pragma unroll
    for (int t = 0; t < 16; ++t) {
        sm += psum[(size_t)(s * 16 + t) * D2_ + c];
        sq += psumsq[(size_t)(s * 16 + t) * D2_ + c];
    }
    const float mu = sm * (1.f / 1024.f);
    const float var = sq * (1.f / 1024.f) - mu * mu;
    const float inv = rsqrtf(var + EPS_);
    const float scale = g2[c] * inv;
    const float bb = be2[c];
    const float* src = (scale >= 0.f) ? maxv : minv;  // BN monotone direction
    for (int k = 0; k < 32; ++k) {
        const float v = src[(size_t)(s * 32 + k) * D2_ + c];
        out[(size_t)(s * 32 + k) * D2_ + c] = fmaxf((v - mu) * scale + bb, 0.f);
    }
}

extern "C" void kernel_launch(void* const* d_in, const int* in_sizes, int n_in,
                              void* d_out, int out_size, void* d_ws, size_t ws_size,
                              hipStream_t stream) {
    const float* h_states = (const float*)d_in[0];
    // d_in[1] seq_start_end: scenes are uniform contiguous blocks (per reference)
    const float* end_pos = (const float*)d_in[2];
    // d_in[3] rel_pos unused
    const float* W_embed = (const float*)d_in[4];
    // d_in[5] b_embed cancels under BN1 mean subtraction
    const float* W1 = (const float*)d_in[6];
    // d_in[7] b1 cancels
    const float* g1 = (const float*)d_in[8];
    const float* be1 = (const float*)d_in[9];
    const float* W2 = (const float*)d_in[10];
    // d_in[11] b2 cancels
    const float* g2 = (const float*)d_in[12];
    const float* be2 = (const float*)d_in[13];
    float* out = (float*)d_out;

    // workspace layout (~97 MiB)
    float* Weq = (float*)d_ws;                 // 1024 f
    float* wbuf = Weq + 1024;                  // 1,048,576 f  -> becomes A
    float* ubuf = wbuf + 1048576;              // 1,048,576 f  -> becomes B
    float* maxv = ubuf + 1048576;              // 2,097,152 f
    float* minv = maxv + 2097152;              // 2,097,152 f
    float* psum = minv + 2097152;              // 1,048,576 f
    float* psumsq = psum + 1048576;            // 1,048,576 f
    u16* w2t = (u16*)(psumsq + 1048576);       // 524,288 u16
    u16* x1 = w2t + 524288;                    // 33,554,432 u16 (64 MiB)

    k_weq<<<dim3(2), dim3(256), 0, stream>>>(W_embed, W1, Weq);
    k_wu<<<dim3(N_), dim3(512), 0, stream>>>(end_pos, h_states, W1, Weq, wbuf, ubuf);
    k_bn1<<<dim3(S_), dim3(512), 0, stream>>>(wbuf, ubuf, g1, be1);
    k_w2t<<<dim3(32, 16), dim3(32, 8), 0, stream>>>(W2, w2t);
    k_x1<<<dim3(16384), dim3(256), 0, stream>>>(wbuf, ubuf, x1);
    k_gemm<<<dim3(8, 512), dim3(256), 0, stream>>>(x1, w2t, maxv, minv, psum, psumsq);
    k_final<<<dim3(4, 64), dim3(256), 0, stream>>>(maxv, minv, psum, psumsq, g2, be2, out);
}

// Round 2
// 231.333 us; speedup vs baseline: 1.0051x; 1.0051x over previous
//
#include <hip/hip_runtime.h>
#include <hip/hip_bf16.h>

#define S_ 64
#define P_ 32
#define N_ 2048
#define H_ 64
#define E_ 64
#define D1_ 512
#define D2_ 1024
#define EPS_ 1e-5f

typedef unsigned short u16;
using bf16x8 = __attribute__((ext_vector_type(8))) __bf16;
using floatx4 = __attribute__((ext_vector_type(4))) float;

__device__ inline u16 f2bf(float x) {
    unsigned u = __float_as_uint(x);
    unsigned r = (u + 0x7fffu + ((u >> 16) & 1u)) >> 16;
    return (u16)r;
}
__device__ inline unsigned bf2pack(float lo, float hi) {
    return (unsigned)f2bf(lo) | ((unsigned)f2bf(hi) << 16);
}

// ---- fused prep: blocks 0..63 -> per-scene Weq+wu+BN1; blocks 64..191 -> W2 transpose ----
// A[n,d] = (w[n,d]-mean_w)*sc+be1 ; B[n,d] = (u[n,d]-mean_u)*sc   (per scene, per d)
__global__ __launch_bounds__(512)
void k_prep(const float* __restrict__ pos, const float* __restrict__ h,
            const float* __restrict__ We, const float* __restrict__ W1,
            const float* __restrict__ g1, const float* __restrict__ be1,
            const float* __restrict__ W2,
            float* __restrict__ A, float* __restrict__ Bv, u16* __restrict__ w2t) {
    __shared__ float smem[64 * 65];  // 16.6 KiB, shared by both branches
    const int bid = blockIdx.x;
    const int tid = threadIdx.x;
    if (bid < S_) {
        // ---------- per-scene prep ----------
        const int s = bid;
        const int d = tid;  // 512 threads = 512 channels
        float* hs = smem;          // 2048 f32: h[j][e], j-major
        float* ps = smem + 2048;   // 64 f32: pos
        for (int i = tid; i < P_ * H_; i += 512) hs[i] = h[(size_t)s * P_ * H_ + i];
        if (tid < 64) ps[tid] = pos[s * 64 + tid];
        __syncthreads();
        // Weq[i][d] = sum_e We[i][e] * W1[e][d]
        float wq0 = 0.f, wq1 = 0.f;
        for (int e = 0; e < E_; ++e) {
            float wv = W1[e * D1_ + d];
            wq0 += We[e] * wv;
            wq1 += We[E_ + e] * wv;
        }
        // w[j] = h[j] @ W1[64:128, d]
        float w[P_];
#pragma unroll
        for (int j = 0; j < P_; ++j) w[j] = 0.f;
        const float4* h4 = (const float4*)hs;
        for (int e4 = 0; e4 < 16; ++e4) {
            const float c0 = W1[(E_ + e4 * 4 + 0) * D1_ + d];
            const float c1 = W1[(E_ + e4 * 4 + 1) * D1_ + d];
            const float c2 = W1[(E_ + e4 * 4 + 2) * D1_ + d];
            const float c3 = W1[(E_ + e4 * 4 + 3) * D1_ + d];
#pragma unroll
            for (int j = 0; j < P_; ++j) {
                float4 hv = h4[j * 16 + e4];
                w[j] += hv.x * c0 + hv.y * c1 + hv.z * c2 + hv.w * c3;
            }
        }
        float sw = 0.f, sww = 0.f, su = 0.f, suu = 0.f;
#pragma unroll
        for (int j = 0; j < P_; ++j) {
            float u = ps[2 * j] * wq0 + ps[2 * j + 1] * wq1;
            w[j] += u;
            sw += w[j]; sww += w[j] * w[j];
            su += u;    suu += u * u;
        }
        const float mw = sw * (1.f / P_), mu = su * (1.f / P_);
        const float var = (sww * (1.f / P_) - mw * mw) + (suu * (1.f / P_) - mu * mu);
        const float sc = rsqrtf(var + EPS_) * g1[d];
        const float bb = be1[d];
#pragma unroll
        for (int j = 0; j < P_; ++j) {
            float u = ps[2 * j] * wq0 + ps[2 * j + 1] * wq1;
            A[(size_t)(s * P_ + j) * D1_ + d] = (w[j] - mw) * sc + bb;
            Bv[(size_t)(s * P_ + j) * D1_ + d] = (u - mu) * sc;
        }
    } else {
        // ---------- W2 transpose+bf16: W2t[n][k] = bf16(W2[k][n]) ----------
        const int b2 = bid - S_;        // 0..127
        const int bi = b2 & 15;         // n tile (64)
        const int bj = b2 >> 4;         // k tile (64)
        const int tx = tid & 63, ty = tid >> 6;  // 64 x 8
        float (*tile)[65] = (float (*)[65])smem;
#pragma unroll
        for (int i = 0; i < 64; i += 8)
            tile[ty + i][tx] = W2[(size_t)(bj * 64 + ty + i) * D2_ + bi * 64 + tx];
        __syncthreads();
#pragma unroll
        for (int i = 0; i < 64; i += 8)
            w2t[(size_t)(bi * 64 + ty + i) * D1_ + bj * 64 + tx] = f2bf(tile[tx][ty + i]);
    }
}

// ---- k_x1: x1[m,d] = bf16(relu(A[s,j,d] - B[s,k,d])), m = s*1024+k*32+j ----
__global__ void k_x1(const float* __restrict__ A, const float* __restrict__ B,
                     u16* __restrict__ x1) {
    const int t = blockIdx.x * 256 + threadIdx.x;  // < 4194304
    const int d8 = t & 63;
    const int r = t >> 6;       // row m, 0..65535
    const int j = r & 31;
    const int sk = r >> 5;      // s*32 + k
    const int s = sk >> 5;
    const float4* Af = (const float4*)(A + (size_t)(s * 32 + j) * D1_ + (d8 << 3));
    const float4* Bf = (const float4*)(B + (size_t)sk * D1_ + (d8 << 3));
    float4 a0 = Af[0], a1 = Af[1];
    float4 b0 = Bf[0], b1 = Bf[1];
    uint4 o;
    o.x = bf2pack(fmaxf(a0.x - b0.x, 0.f), fmaxf(a0.y - b0.y, 0.f));
    o.y = bf2pack(fmaxf(a0.z - b0.z, 0.f), fmaxf(a0.w - b0.w, 0.f));
    o.z = bf2pack(fmaxf(a1.x - b1.x, 0.f), fmaxf(a1.y - b1.y, 0.f));
    o.w = bf2pack(fmaxf(a1.z - b1.z, 0.f), fmaxf(a1.w - b1.w, 0.f));
    *(uint4*)(x1 + ((size_t)r << 9) + (d8 << 3)) = o;
}

// ---- GEMM [65536x512]x[512x1024] with fused j-max/min + BN2 stats ----
// grid (512, 8): x = row tile (XCD-aligned: the 8 col-tile siblings sharing an
// x1 strip have linear ids spaced 512 apart -> same id%8 -> same XCD L2).
__global__ __launch_bounds__(256)
void k_gemm(const u16* __restrict__ x1, const u16* __restrict__ w2t,
            float* __restrict__ maxv, float* __restrict__ minv,
            float* __restrict__ psum, float* __restrict__ psumsq) {
    __shared__ u16 As[128 * 64];
    __shared__ u16 Bs[128 * 64];
    const int rowt = blockIdx.x;  // 0..511
    const int colt = blockIdx.y;  // 0..7
    const int M0 = rowt << 7, N0 = colt << 7;
    const int tid = threadIdx.x;
    const int wave = tid >> 6, lane = tid & 63;
    const int wm = wave >> 1, wn = wave & 1;
    const int quad = lane >> 4, l16 = lane & 15;
    const int lrow = lane >> 3, lchk = lane & 7;
    const int gchk = lchk ^ lrow;  // XOR-swizzled global chunk for this lane

    floatx4 acc[4][4] = {};

    const int arow = wave << 5;  // this wave stages rows arow..arow+31
    for (int it = 0; it < 8; ++it) {
        const int k0 = it << 6;
#pragma unroll
        for (int t = 0; t < 4; ++t) {
            const int rbase = arow + (t << 3);
            const u16* ga = x1 + (size_t)(M0 + rbase + lrow) * 512 + (k0 + (gchk << 3));
            const u16* gb = w2t + (size_t)(N0 + rbase + lrow) * 512 + (k0 + (gchk << 3));
            __builtin_amdgcn_global_load_lds(
                (const __attribute__((address_space(1))) void*)ga,
                (__attribute__((address_space(3))) void*)(As + (rbase << 6)), 16, 0, 0);
            __builtin_amdgcn_global_load_lds(
                (const __attribute__((address_space(1))) void*)gb,
                (__attribute__((address_space(3))) void*)(Bs + (rbase << 6)), 16, 0, 0);
        }
        __syncthreads();
#pragma unroll
        for (int kk = 0; kk < 2; ++kk) {
            bf16x8 af[4], bfr[4];
#pragma unroll
            for (int tm = 0; tm < 4; ++tm) {
                const int row = (wm << 6) + (tm << 4) + l16;
                const int sc = ((kk << 2) + quad) ^ (row & 7);
                af[tm] = *(const bf16x8*)(As + (row << 6) + (sc << 3));
            }
#pragma unroll
            for (int tn = 0; tn < 4; ++tn) {
                const int row = (wn << 6) + (tn << 4) + l16;
                const int sc = ((kk << 2) + quad) ^ (row & 7);
                bfr[tn] = *(const bf16x8*)(Bs + (row << 6) + (sc << 3));
            }
#pragma unroll
            for (int tm = 0; tm < 4; ++tm)
#pragma unroll
                for (int tn = 0; tn < 4; ++tn)
                    acc[tm][tn] = __builtin_amdgcn_mfma_f32_16x16x32_bf16(
                        af[tm], bfr[tn], acc[tm][tn], 0, 0, 0);
        }
        __syncthreads();
    }

    // epilogue: reduce over j (32 rows) for max/min; 64-row partial sums for BN2
    const int s = rowt >> 3, rb = rowt & 7;
#pragma unroll
    for (int tn = 0; tn < 4; ++tn) {
        const int col = N0 + (wn << 6) + (tn << 4) + l16;
        float wsum = 0.f, wsq = 0.f;
#pragma unroll
        for (int gp = 0; gp < 2; ++gp) {
            float vmax = -3.4e38f, vmin = 3.4e38f, vs = 0.f, vq = 0.f;
#pragma unroll
            for (int tm = gp * 2; tm < gp * 2 + 2; ++tm)
#pragma unroll
                for (int r = 0; r < 4; ++r) {
                    float v = acc[tm][tn][r];
                    vmax = fmaxf(vmax, v);
                    vmin = fminf(vmin, v);
                    vs += v;
                    vq += v * v;
                }
#pragma unroll
            for (int off = 16; off < 64; off <<= 1) {
                vmax = fmaxf(vmax, __shfl_xor(vmax, off));
                vmin = fminf(vmin, __shfl_xor(vmin, off));
                vs += __shfl_xor(vs, off);
                vq += __shfl_xor(vq, off);
            }
            if (quad == 0) {
                const int kg = (rowt << 2) + (wm << 1) + gp;  // global ped row 0..2047
                maxv[(size_t)kg * D2_ + col] = vmax;
                minv[(size_t)kg * D2_ + col] = vmin;
            }
            wsum += vs;
            wsq += vq;
        }
        if (quad == 0) {
            const int slot = (s << 4) + (rb << 1) + wm;  // 16 slots per scene
            psum[(size_t)slot * D2_ + col] = wsum;
            psumsq[(size_t)slot * D2_ + col] = wsq;
        }
    }
}

// ---- BN2 + relu on the j-maxed values ----
__global__ void k_final(const float* __restrict__ maxv, const float* __restrict__ minv,
                        const float* __restrict__ psum, const float* __restrict__ psumsq,
                        const float* __restrict__ g2, const float* __restrict__ be2,
                        float* __restrict__ out) {
    const int c = blockIdx.x * 256 + threadIdx.x;  // 0..1023
    const int s = blockIdx.y;
    float sm = 0.f, sq = 0.f;
#pragma unroll
    for (int t = 0; t < 16; ++t) {
        sm += psum[(size_t)(s * 16 + t) * D2_ + c];
        sq += psumsq[(size_t)(s * 16 + t) * D2_ + c];
    }
    const float mu = sm * (1.f / 1024.f);
    const float var = sq * (1.f / 1024.f) - mu * mu;
    const float inv = rsqrtf(var + EPS_);
    const float scale = g2[c] * inv;
    const float bb = be2[c];
    const float* src = (scale >= 0.f) ? maxv : minv;  // BN monotone direction
    for (int k = 0; k < 32; ++k) {
        const float v = src[(size_t)(s * 32 + k) * D2_ + c];
        out[(size_t)(s * 32 + k) * D2_ + c] = fmaxf((v - mu) * scale + bb, 0.f);
    }
}

extern "C" void kernel_launch(void* const* d_in, const int* in_sizes, int n_in,
                              void* d_out, int out_size, void* d_ws, size_t ws_size,
                              hipStream_t stream) {
    const float* h_states = (const float*)d_in[0];
    const float* end_pos = (const float*)d_in[2];
    const float* W_embed = (const float*)d_in[4];
    const float* W1 = (const float*)d_in[6];
    const float* g1 = (const float*)d_in[8];
    const float* be1 = (const float*)d_in[9];
    const float* W2 = (const float*)d_in[10];
    const float* g2 = (const float*)d_in[12];
    const float* be2 = (const float*)d_in[13];
    float* out = (float*)d_out;

    // workspace layout
    float* Abuf = (float*)d_ws;                // 1,048,576 f
    float* Bbuf = Abuf + 1048576;              // 1,048,576 f
    float* maxv = Bbuf + 1048576;              // 2,097,152 f
    float* minv = maxv + 2097152;              // 2,097,152 f
    float* psum = minv + 2097152;              // 1,048,576 f
    float* psumsq = psum + 1048576;            // 1,048,576 f
    u16* w2t = (u16*)(psumsq + 1048576);       // 524,288 u16
    u16* x1 = w2t + 524288;                    // 33,554,432 u16 (64 MiB)

    k_prep<<<dim3(S_ + 128), dim3(512), 0, stream>>>(end_pos, h_states, W_embed, W1,
                                                     g1, be1, W2, Abuf, Bbuf, w2t);
    k_x1<<<dim3(16384), dim3(256), 0, stream>>>(Abuf, Bbuf, x1);
    k_gemm<<<dim3(512, 8), dim3(256), 0, stream>>>(x1, w2t, maxv, minv, psum, psumsq);
    k_final<<<dim3(4, 64), dim3(256), 0, stream>>>(maxv, minv, psum, psumsq, g2, be2, out);
}